// Round 12
// baseline (188.212 us; speedup 1.0000x reference)
//
#include <hip/hip_runtime.h>

#define NB   32
#define NPER 512
#define NN   16384
#define EE   262144
#define DD   128
#define AS   2048
#define KC   64

using short8   = __attribute__((ext_vector_type(8))) short;
using floatx4  = __attribute__((ext_vector_type(4))) float;
using ushort4v = __attribute__((ext_vector_type(4))) unsigned short;

typedef __attribute__((address_space(3))) unsigned int lds_u32;
typedef const __attribute__((address_space(1))) unsigned int gbl_u32;

static __device__ __forceinline__ void gload16(const unsigned short* g, unsigned short* l) {
    __builtin_amdgcn_global_load_lds((gbl_u32*)g, (lds_u32*)l, 16, 0, 0);
}
static __device__ __forceinline__ float bits2f(unsigned int u) {
    union { unsigned int i; float f; } z; z.i = u << 16; return z.f;
}
static __device__ __forceinline__ unsigned short f2b(float x) {
    union { float f; unsigned int u; } v; v.f = x;
    unsigned int r = v.u + 0x7fffu + ((v.u >> 16) & 1u);
    return (unsigned short)(r >> 16);
}
// exact for non-negative ints <= 256
static __device__ __forceinline__ unsigned short f2b_exact(float x) {
    union { float f; unsigned int u; } v; v.f = x;
    return (unsigned short)(v.u >> 16);
}

union PrepSMem {
    unsigned short fT[128 * 136];
    float tl[32][33];
    struct { unsigned short glA[4096]; unsigned short glB[4096]; float gcred[4]; } gg;
};
__global__ void prep_kernel(const float* __restrict__ h, unsigned short* __restrict__ bundle,
                            unsigned short* __restrict__ hT, const int* __restrict__ esrc,
                            const int* __restrict__ edst, unsigned int* __restrict__ Acnt,
                            const float* __restrict__ Wf, const float* __restrict__ Wp,
                            const float* __restrict__ bp,
                            unsigned short* __restrict__ WfT, unsigned short* __restrict__ WpT,
                            float* __restrict__ Gf, float* __restrict__ uF,
                            float* __restrict__ cF) {
    __shared__ PrepSMem sm;
    int b = blockIdx.x, t = threadIdx.x;
    if (b < 128) {
        int node0 = b * 128;
        int r = t >> 1, hf = t & 1;
        const float4* h4 = reinterpret_cast<const float4*>(h + (size_t)(node0 + r) * 128 + hf * 64);
        unsigned short* bo = bundle + (size_t)(node0 + r) * 256 + hf * 64;
#pragma unroll
        for (int i = 0; i < 16; i++) {
            float4 v = h4[i];
            ushort4v o = { f2b(v.x), f2b(v.y), f2b(v.z), f2b(v.w) };
            *reinterpret_cast<ushort4v*>(bo + 4 * i) = o;
            int c = hf * 64 + 4 * i;
            sm.fT[(c + 0) * 136 + r] = o.x;
            sm.fT[(c + 1) * 136 + r] = o.y;
            sm.fT[(c + 2) * 136 + r] = o.z;
            sm.fT[(c + 3) * 136 + r] = o.w;
        }
        __syncthreads();
        int c = t >> 1, nh = t & 1;
        const uint4* src = reinterpret_cast<const uint4*>(&sm.fT[c * 136 + nh * 64]);
        uint4* dst = reinterpret_cast<uint4*>(hT + (size_t)c * NN + node0 + nh * 64);
#pragma unroll
        for (int i = 0; i < 8; i++) dst[i] = src[i];
    } else if (b < 1152) {
        int e = (b - 128) * 256 + t;
        int d = edst[e], sl = esrc[e] & 511;
        int idx = d * 512 + sl;
        atomicAdd(&Acnt[idx >> 2], 1u << (8 * (idx & 3)));
    } else if (b < 1696) {
        int tb = b - 1152;
        int bx = tb % 68, by = tb / 68;
        int tx = t & 31, ty = t >> 5;
        const float* in; unsigned short* out; int C, cb;
        if (bx < DD / 32) { in = Wf; out = WfT; C = DD; cb = bx; }
        else              { in = Wp; out = WpT; C = AS; cb = bx - DD / 32; }
        int c0 = cb * 32, r0 = by * 32;
        for (int i = 0; i < 4; i++)
            sm.tl[ty + 8 * i][tx] = in[(size_t)(r0 + ty + 8 * i) * C + c0 + tx];
        __syncthreads();
        for (int i = 0; i < 4; i++)
            out[(size_t)(c0 + ty + 8 * i) * 256 + r0 + tx] = f2b(sm.tl[tx][ty + 8 * i]);
    } else {
        // ggemm: G = Wp Wp^T from fp32, staged with in-register bf16 cast
        int b2 = b - 1696;
        int ks = b2 >> 2, ti = (b2 >> 1) & 1, tj = b2 & 1;
        int wv = t >> 6, lane = t & 63;
        int mw = wv >> 1, nw = wv & 1, q = lane >> 4, lm = lane & 15;
        int swz = q ^ ((lm >> 1) & 3);
        floatx4 acc[4][4];
#pragma unroll
        for (int mi = 0; mi < 4; mi++)
#pragma unroll
            for (int ni = 0; ni < 4; ni++) acc[mi][ni] = (floatx4)0.f;
        for (int ki = 0; ki < 16; ki++) {
            int k0 = ks * 512 + ki * 32;
#pragma unroll
            for (int half = 0; half < 2; half++) {
                int u = t + 256 * half;
                int row = u >> 2, c = u & 3;
                int cs = c ^ ((row >> 1) & 3);
                const float4* sa = reinterpret_cast<const float4*>(
                    Wp + (size_t)(ti * 128 + row) * 2048 + k0 + c * 8);
                float4 v0 = sa[0], v1 = sa[1];
                ushort4v p0 = { f2b(v0.x), f2b(v0.y), f2b(v0.z), f2b(v0.w) };
                ushort4v p1 = { f2b(v1.x), f2b(v1.y), f2b(v1.z), f2b(v1.w) };
                *reinterpret_cast<ushort4v*>(&sm.gg.glA[(row * 4 + cs) * 8]) = p0;
                *reinterpret_cast<ushort4v*>(&sm.gg.glA[(row * 4 + cs) * 8 + 4]) = p1;
                const float4* sb = reinterpret_cast<const float4*>(
                    Wp + (size_t)(tj * 128 + row) * 2048 + k0 + c * 8);
                float4 w0 = sb[0], w1 = sb[1];
                ushort4v q0 = { f2b(w0.x), f2b(w0.y), f2b(w0.z), f2b(w0.w) };
                ushort4v q1 = { f2b(w1.x), f2b(w1.y), f2b(w1.z), f2b(w1.w) };
                *reinterpret_cast<ushort4v*>(&sm.gg.glB[(row * 4 + cs) * 8]) = q0;
                *reinterpret_cast<ushort4v*>(&sm.gg.glB[(row * 4 + cs) * 8 + 4]) = q1;
            }
            __syncthreads();
            short8 aF[4], bF[4];
#pragma unroll
            for (int mi = 0; mi < 4; mi++)
                aF[mi] = *reinterpret_cast<const short8*>(&sm.gg.glA[((64 * mw + 16 * mi + lm) * 4 + swz) * 8]);
#pragma unroll
            for (int ni = 0; ni < 4; ni++)
                bF[ni] = *reinterpret_cast<const short8*>(&sm.gg.glB[((64 * nw + 16 * ni + lm) * 4 + swz) * 8]);
#pragma unroll
            for (int mi = 0; mi < 4; mi++)
#pragma unroll
                for (int ni = 0; ni < 4; ni++)
                    acc[mi][ni] = __builtin_amdgcn_mfma_f32_16x16x32_bf16(aF[mi], bF[ni], acc[mi][ni], 0, 0, 0);
            __syncthreads();
        }
#pragma unroll
        for (int mi = 0; mi < 4; mi++)
#pragma unroll
            for (int ni = 0; ni < 4; ni++)
#pragma unroll
                for (int r = 0; r < 4; r++)
                    atomicAdd(&Gf[(size_t)(ti * 128 + 64 * mw + 16 * mi + 4 * q + r) * 256 +
                                  tj * 128 + 64 * nw + 16 * ni + lm], acc[mi][ni][r]);
        if (tj == 0) {
            int row = t >> 1, jh = t & 1;
            const float* wr = Wp + (size_t)(ti * 128 + row) * 2048 + ks * 512 + jh * 256;
            const float* br = bp + ks * 512 + jh * 256;
            float s = 0.f;
            for (int j = 0; j < 256; j++) s += wr[j] * br[j];
            atomicAdd(&uF[ti * 128 + row], s);
        }
        if (b2 == 0) {
            float s = 0.f;
            for (int j = t; j < 2048; j += 256) { float v = bp[j]; s += v * v; }
#pragma unroll
            for (int d = 1; d < 64; d <<= 1) s += __shfl_xor(s, d, 64);
            if (lane == 0) sm.gg.gcred[wv] = s;
            __syncthreads();
            if (t == 0) atomicAdd(cF, sm.gg.gcred[0] + sm.gg.gcred[1] + sm.gg.gcred[2] + sm.gg.gcred[3]);
        }
    }
}

__global__ __launch_bounds__(256) void agg_h_mfma_kernel(
    const unsigned int* __restrict__ Acnt, const unsigned short* __restrict__ hT,
    unsigned short* __restrict__ bundle, unsigned short* __restrict__ Aadj,
    const float* __restrict__ Gf, unsigned short* __restrict__ Gb) {
    __shared__ alignas(16) unsigned short lA[64 * 512];
    __shared__ float rs[64];
    int tid = threadIdx.x, bx = blockIdx.x;
    if (bx >= 256) {
        int base = (bx - 256) * 16384;
        for (int i = 0; i < 16; i++) {
            int idx = base + i * 1024 + tid * 4;
            float4 v = *reinterpret_cast<const float4*>(Gf + idx);
            ushort4v o = { f2b(v.x), f2b(v.y), f2b(v.z), f2b(v.w) };
            *reinterpret_cast<ushort4v*>(&Gb[idx]) = o;
        }
        return;
    }
    int r0 = bx * 64, g = bx >> 3;
    int wv = tid >> 6, lane = tid & 63, q = lane >> 4, lm = lane & 15;
    int mw = wv >> 1, nw = wv & 1;
    if (tid < 64) rs[tid] = 0.f;
    __syncthreads();
#pragma unroll
    for (int j = 0; j < 8; j++) {
        int ub = tid + 256 * j;
        int row = ub >> 5, kb = ub & 31;
        uint4 w = reinterpret_cast<const uint4*>(Acnt)[(size_t)(r0 + row) * 32 + kb];
        unsigned int wa[4] = { w.x, w.y, w.z, w.w };
        unsigned short ob[16];
        float sum = 0.f;
#pragma unroll
        for (int i = 0; i < 4; i++) {
#pragma unroll
            for (int bb = 0; bb < 4; bb++) {
                float fv = (float)((wa[i] >> (8 * bb)) & 0xffu);
                sum += fv;
                ob[4 * i + bb] = f2b_exact(fv);
            }
        }
        atomicAdd(&rs[row], sum);
        uint4* gdst = reinterpret_cast<uint4*>(&Aadj[(size_t)(r0 + row) * 512 + kb * 16]);
        gdst[0] = *reinterpret_cast<const uint4*>(&ob[0]);
        gdst[1] = *reinterpret_cast<const uint4*>(&ob[8]);
#pragma unroll
        for (int jj = 0; jj < 2; jj++) {
            int pos = (kb * 2 + jj) ^ (row & 7);
            *reinterpret_cast<uint4*>(&lA[(row * 64 + pos) * 8]) =
                *reinterpret_cast<const uint4*>(&ob[8 * jj]);
        }
    }
    floatx4 acc[2][4];
#pragma unroll
    for (int mt = 0; mt < 2; mt++)
#pragma unroll
        for (int nt = 0; nt < 4; nt++) acc[mt][nt] = (floatx4)0.f;
    __syncthreads();
    const unsigned short* Bb = hT + (size_t)(64 * nw + lm) * NN + g * 512 + (q << 3);
    short8 bF[2][4];
#pragma unroll
    for (int nt = 0; nt < 4; nt++)
        bF[0][nt] = *reinterpret_cast<const short8*>(Bb + (size_t)16 * nt * NN);
    for (int ki = 0; ki < 16; ki++) {
        if (ki < 15) {
#pragma unroll
            for (int nt = 0; nt < 4; nt++)
                bF[(ki + 1) & 1][nt] =
                    *reinterpret_cast<const short8*>(Bb + (size_t)16 * nt * NN + (ki + 1) * 32);
        }
        short8 aF[2];
        int swz = (4 * ki + q) ^ (lm & 7);
#pragma unroll
        for (int mt = 0; mt < 2; mt++)
            aF[mt] = *reinterpret_cast<const short8*>(&lA[((32 * mw + 16 * mt + lm) * 64 + swz) * 8]);
#pragma unroll
        for (int mt = 0; mt < 2; mt++)
#pragma unroll
            for (int nt = 0; nt < 4; nt++)
                acc[mt][nt] = __builtin_amdgcn_mfma_f32_16x16x32_bf16(aF[mt], bF[ki & 1][nt],
                                                                      acc[mt][nt], 0, 0, 0);
    }
#pragma unroll
    for (int mt = 0; mt < 2; mt++)
#pragma unroll
        for (int r = 0; r < 4; r++) {
            int row = 32 * mw + 16 * mt + 4 * q + r;
            float inv = 1.0f / fmaxf(rs[row], 1.0f);
#pragma unroll
            for (int nt = 0; nt < 4; nt++)
                bundle[(size_t)(r0 + row) * 256 + 128 + 64 * nw + 16 * nt + lm] =
                    f2b(acc[mt][nt][r] * inv);
        }
}

union FPSMem {
    struct { unsigned short lA[4096]; unsigned short lB[4096]; float red[256]; } feat;
    struct { unsigned short lA[16384]; float raw[4352]; float ssq[256]; float rn[64];
             float uL[256]; } pool;
};
__global__ __launch_bounds__(256) void featpool_kernel(
    const unsigned short* __restrict__ bundle, const unsigned short* __restrict__ WfT,
    const unsigned short* __restrict__ WpT, const unsigned short* __restrict__ Gb,
    const float* __restrict__ bfe, const float* __restrict__ bp,
    const float* __restrict__ uF, const float* __restrict__ cF,
    unsigned short* __restrict__ featT, unsigned short* __restrict__ sT) {
    __shared__ FPSMem sm;
    int tid = threadIdx.x, b = blockIdx.x;
    if (b < 128) {
        int r0 = b * 128;
        int wv = tid >> 6, lane = tid & 63;
        int mw = wv >> 1, nw = wv & 1, q = lane >> 4, lm = lane & 15;
        int rowS0 = tid >> 2,         cS0 = (tid & 3) ^ ((rowS0 >> 1) & 3);
        int rowS1 = (tid + 256) >> 2, cS1 = ((tid + 256) & 3) ^ ((rowS1 >> 1) & 3);
        int swz = q ^ ((lm >> 1) & 3);
        floatx4 acc[4][4];
#pragma unroll
        for (int mi = 0; mi < 4; mi++)
#pragma unroll
            for (int ni = 0; ni < 4; ni++) acc[mi][ni] = (floatx4)0.f;
        for (int k0 = 0; k0 < 256; k0 += 32) {
            gload16(bundle + (size_t)(r0 + rowS0) * 256 + k0 + 8 * cS0, &sm.feat.lA[tid * 8]);
            gload16(bundle + (size_t)(r0 + rowS1) * 256 + k0 + 8 * cS1, &sm.feat.lA[(tid + 256) * 8]);
            gload16(WfT + (size_t)rowS0 * 256 + k0 + 8 * cS0, &sm.feat.lB[tid * 8]);
            gload16(WfT + (size_t)rowS1 * 256 + k0 + 8 * cS1, &sm.feat.lB[(tid + 256) * 8]);
            __syncthreads();
            short8 aF[4], bF[4];
#pragma unroll
            for (int mi = 0; mi < 4; mi++)
                aF[mi] = *reinterpret_cast<const short8*>(&sm.feat.lA[((64 * mw + 16 * mi + lm) * 4 + swz) * 8]);
#pragma unroll
            for (int ni = 0; ni < 4; ni++)
                bF[ni] = *reinterpret_cast<const short8*>(&sm.feat.lB[((64 * nw + 16 * ni + lm) * 4 + swz) * 8]);
#pragma unroll
            for (int mi = 0; mi < 4; mi++)
#pragma unroll
                for (int ni = 0; ni < 4; ni++)
                    acc[mi][ni] = __builtin_amdgcn_mfma_f32_16x16x32_bf16(aF[mi], bF[ni], acc[mi][ni], 0, 0, 0);
            __syncthreads();
        }
#pragma unroll
        for (int ni = 0; ni < 4; ni++) {
            float bv = bfe[64 * nw + 16 * ni + lm];
#pragma unroll
            for (int mi = 0; mi < 4; mi++)
#pragma unroll
                for (int r = 0; r < 4; r++) acc[mi][ni][r] += bv;
        }
#pragma unroll
        for (int mi = 0; mi < 4; mi++)
#pragma unroll
            for (int r = 0; r < 4; r++) {
                float p = 0.f;
#pragma unroll
                for (int ni = 0; ni < 4; ni++) p += acc[mi][ni][r] * acc[mi][ni][r];
                p += __shfl_xor(p, 1, 64);
                p += __shfl_xor(p, 2, 64);
                p += __shfl_xor(p, 4, 64);
                p += __shfl_xor(p, 8, 64);
                if (lm == 0) sm.feat.red[nw * 128 + 64 * mw + 16 * mi + 4 * q + r] = p;
            }
        __syncthreads();
#pragma unroll
        for (int mi = 0; mi < 4; mi++) {
            float rrn[4];
#pragma unroll
            for (int r = 0; r < 4; r++) {
                int rl = 64 * mw + 16 * mi + 4 * q + r;
                rrn[r] = 1.0f / fmaxf(sqrtf(sm.feat.red[rl] + sm.feat.red[128 + rl]), 1e-12f);
            }
#pragma unroll
            for (int ni = 0; ni < 4; ni++) {
                int col = 64 * nw + 16 * ni + lm;
                ushort4v pk = { f2b(fmaxf(acc[mi][ni][0] * rrn[0], 0.f)),
                                f2b(fmaxf(acc[mi][ni][1] * rrn[1], 0.f)),
                                f2b(fmaxf(acc[mi][ni][2] * rrn[2], 0.f)),
                                f2b(fmaxf(acc[mi][ni][3] * rrn[3], 0.f)) };
                *reinterpret_cast<ushort4v*>(
                    &featT[(size_t)col * NN + r0 + 64 * mw + 16 * mi + 4 * q]) = pk;
            }
        }
    } else {
        int bx = b - 128;
        int r0 = bx * 64, g = bx >> 3;
        int wv = tid >> 6, lane = tid & 63, q = lane >> 4, lm = lane & 15;
#pragma unroll
        for (int j = 0; j < 8; j++) {
            int u = tid + 256 * j;
            int row = u >> 5;
            int chunk = (u & 31) ^ (row & 7);
            gload16(bundle + (size_t)(r0 + row) * 256 + chunk * 8, &sm.pool.lA[u * 8]);
        }
        sm.pool.uL[tid] = uF[tid];
        __syncthreads();
        {
            const unsigned short* Bb = Gb + ((size_t)(wv * 64 + lm) << 8) + (q << 3);
            short8 bF[2][4];
#pragma unroll
            for (int ni = 0; ni < 4; ni++)
                bF[0][ni] = *reinterpret_cast<const short8*>(Bb + (ni << 12));
            floatx4 acc[4][4];
#pragma unroll
            for (int mi = 0; mi < 4; mi++)
#pragma unroll
                for (int ni = 0; ni < 4; ni++) acc[mi][ni] = (floatx4)0.f;
#pragma unroll
            for (int k = 0; k < 8; k++) {
                if (k < 7) {
#pragma unroll
                    for (int ni = 0; ni < 4; ni++)
                        bF[(k + 1) & 1][ni] =
                            *reinterpret_cast<const short8*>(Bb + (ni << 12) + ((k + 1) << 5));
                }
                short8 aF[4];
                int swz = (4 * k + q) ^ (lm & 7);
#pragma unroll
                for (int mi = 0; mi < 4; mi++)
                    aF[mi] = *reinterpret_cast<const short8*>(&sm.pool.lA[((16 * mi + lm) * 32 + swz) * 8]);
#pragma unroll
                for (int mi = 0; mi < 4; mi++)
#pragma unroll
                    for (int ni = 0; ni < 4; ni++)
                        acc[mi][ni] = __builtin_amdgcn_mfma_f32_16x16x32_bf16(aF[mi], bF[k & 1][ni],
                                                                              acc[mi][ni], 0, 0, 0);
            }
            float uc[4];
#pragma unroll
            for (int ni = 0; ni < 4; ni++) uc[ni] = sm.pool.uL[64 * wv + 16 * ni + lm];
#pragma unroll
            for (int mi = 0; mi < 4; mi++)
#pragma unroll
                for (int r = 0; r < 4; r++) {
                    int row = 16 * mi + 4 * q + r;
                    float p = 0.f;
#pragma unroll
                    for (int ni = 0; ni < 4; ni++) {
                        int col = 64 * wv + 16 * ni + lm;
                        int cu = (col >> 3) ^ (row & 7);
                        float xv = bits2f((unsigned int)sm.pool.lA[(row * 32 + cu) * 8 + (col & 7)]);
                        p += (acc[mi][ni][r] + 2.f * uc[ni]) * xv;
                    }
                    p += __shfl_xor(p, 1, 64);
                    p += __shfl_xor(p, 2, 64);
                    p += __shfl_xor(p, 4, 64);
                    p += __shfl_xor(p, 8, 64);
                    if (lm == 0) sm.pool.ssq[wv * 64 + row] = p;
                }
        }
        {
            const unsigned short* Bb2 = WpT + (size_t)(g * KC + 16 * wv + lm) * 256 + (q << 3);
            short8 b2[2];
            b2[0] = *reinterpret_cast<const short8*>(Bb2);
            floatx4 acc2[4];
#pragma unroll
            for (int mi = 0; mi < 4; mi++) acc2[mi] = (floatx4)0.f;
#pragma unroll
            for (int k = 0; k < 8; k++) {
                if (k < 7) b2[(k + 1) & 1] = *reinterpret_cast<const short8*>(Bb2 + ((k + 1) << 5));
                short8 aF[4];
                int swz = (4 * k + q) ^ (lm & 7);
#pragma unroll
                for (int mi = 0; mi < 4; mi++)
                    aF[mi] = *reinterpret_cast<const short8*>(&sm.pool.lA[((16 * mi + lm) * 32 + swz) * 8]);
#pragma unroll
                for (int mi = 0; mi < 4; mi++)
                    acc2[mi] = __builtin_amdgcn_mfma_f32_16x16x32_bf16(aF[mi], b2[k & 1], acc2[mi], 0, 0, 0);
            }
            float bv = bp[g * KC + 16 * wv + lm];
#pragma unroll
            for (int mi = 0; mi < 4; mi++)
#pragma unroll
                for (int r = 0; r < 4; r++)
                    sm.pool.raw[(16 * mi + 4 * q + r) * 68 + 16 * wv + lm] = acc2[mi][r] + bv;
        }
        __syncthreads();
        if (tid < 64)
            sm.pool.rn[tid] = 1.0f / fmaxf(sqrtf(sm.pool.ssq[tid] + sm.pool.ssq[64 + tid] +
                                           sm.pool.ssq[128 + tid] + sm.pool.ssq[192 + tid] + cF[0]), 1e-12f);
        __syncthreads();
        {
            int row = tid >> 2, j = tid & 3;
            int nloc = ((bx & 7) << 6) + row;
            float rn = sm.pool.rn[row];
            float v[16];
            float mx = -1e30f;
#pragma unroll
            for (int c4 = 0; c4 < 4; c4++) {
                float4 rv = *reinterpret_cast<const float4*>(&sm.pool.raw[row * 68 + 16 * j + 4 * c4]);
                v[4 * c4 + 0] = fmaxf(rv.x * rn, 0.f);
                v[4 * c4 + 1] = fmaxf(rv.y * rn, 0.f);
                v[4 * c4 + 2] = fmaxf(rv.z * rn, 0.f);
                v[4 * c4 + 3] = fmaxf(rv.w * rn, 0.f);
            }
#pragma unroll
            for (int c = 0; c < 16; c++) mx = fmaxf(mx, v[c]);
            mx = fmaxf(mx, __shfl_xor(mx, 1, 64));
            mx = fmaxf(mx, __shfl_xor(mx, 2, 64));
            float z = 0.f;
#pragma unroll
            for (int c = 0; c < 16; c++) { v[c] = __expf(v[c] - mx); z += v[c]; }
            z += __shfl_xor(z, 1, 64);
            z += __shfl_xor(z, 2, 64);
            float iz = 1.0f / z;
#pragma unroll
            for (int c4 = 0; c4 < 4; c4++) {
                size_t tb = (size_t)(g * KC + 16 * j + 4 * c4) * NPER + nloc;
                sT[tb] = f2b(v[4 * c4 + 0] * iz);
                sT[tb + NPER] = f2b(v[4 * c4 + 1] * iz);
                sT[tb + 2 * NPER] = f2b(v[4 * c4 + 2] * iz);
                sT[tb + 3 * NPER] = f2b(v[4 * c4 + 3] * iz);
            }
        }
    }
}

__global__ __launch_bounds__(256) void as_mfma_kernel(
    const unsigned short* __restrict__ sT, const unsigned short* __restrict__ Aadj,
    unsigned short* __restrict__ asT) {
    __shared__ alignas(16) unsigned short lS[64 * 512];
    int tid = threadIdx.x, bx = blockIdx.x;
    int g = bx >> 1, half = bx & 1;
    int wv = tid >> 6, lane = tid & 63, q = lane >> 4, lm = lane & 15;
#pragma unroll
    for (int j = 0; j < 16; j++) {
        int u = tid + 256 * j;
        int row = u >> 6, cu = (u & 63) ^ (row & 7);
        gload16(sT + (size_t)(g * KC + row) * NPER + cu * 8, &lS[u * 8]);
    }
    floatx4 acc[4][4];
#pragma unroll
    for (int mi = 0; mi < 4; mi++)
#pragma unroll
        for (int nt = 0; nt < 4; nt++) acc[mi][nt] = (floatx4)0.f;
    __syncthreads();
    int dbase = half * 256 + wv * 64;
    const unsigned short* Bb = Aadj + (size_t)(g * 512 + dbase + lm) * 512 + (q << 3);
    short8 bF[2][4];
#pragma unroll
    for (int nt = 0; nt < 4; nt++)
        bF[0][nt] = *reinterpret_cast<const short8*>(Bb + (size_t)16 * nt * 512);
    for (int ki = 0; ki < 16; ki++) {
        if (ki < 15) {
#pragma unroll
            for (int nt = 0; nt < 4; nt++)
                bF[(ki + 1) & 1][nt] =
                    *reinterpret_cast<const short8*>(Bb + (size_t)16 * nt * 512 + (ki + 1) * 32);
        }
        short8 aF[4];
        int swz = (4 * ki + q) ^ (lm & 7);
#pragma unroll
        for (int mi = 0; mi < 4; mi++)
            aF[mi] = *reinterpret_cast<const short8*>(&lS[((16 * mi + lm) * 64 + swz) * 8]);
#pragma unroll
        for (int mi = 0; mi < 4; mi++)
#pragma unroll
            for (int nt = 0; nt < 4; nt++)
                acc[mi][nt] = __builtin_amdgcn_mfma_f32_16x16x32_bf16(aF[mi], bF[ki & 1][nt],
                                                                      acc[mi][nt], 0, 0, 0);
    }
#pragma unroll
    for (int mi = 0; mi < 4; mi++)
#pragma unroll
        for (int r = 0; r < 4; r++) {
            int row = 16 * mi + 4 * q + r;
#pragma unroll
            for (int nt = 0; nt < 4; nt++)
                asT[(size_t)(g * KC + row) * NPER + dbase + 16 * nt + lm] = f2b(acc[mi][nt][r]);
        }
}

__global__ __launch_bounds__(256) void hnew_adj2_kernel(
    const unsigned short* __restrict__ sT, const unsigned short* __restrict__ featT,
    const unsigned short* __restrict__ asT, float* __restrict__ adjf,
    float* __restrict__ hnewf) {
    __shared__ alignas(16) unsigned short lS[1024 * 8];
    __shared__ alignas(16) unsigned short lF[2048 * 8];
    __shared__ alignas(16) unsigned short lAS[1024 * 8];
    int tid = threadIdx.x, b = blockIdx.x;
    if (b >= 32) {
        uint4 z = { 0u, 0u, 0u, 0u };
        for (int row = b - 32; row < AS; row += 224) {
            int g = row >> 6;
            uint4* out = reinterpret_cast<uint4*>(adjf + (size_t)row * AS);
            for (int i = tid; i < 512; i += 256)
                if (i < g * 16 || i >= g * 16 + 16) out[i] = z;
        }
        return;
    }
    int g = b;
    int wv = tid >> 6, lane = tid & 63, q = lane >> 4, lm = lane & 15;
    bool isH = (wv < 2);
    floatx4 accH[4][4];
    floatx4 accA[4][2];
#pragma unroll
    for (int mi = 0; mi < 4; mi++) {
#pragma unroll
        for (int ni = 0; ni < 4; ni++) accH[mi][ni] = (floatx4)0.f;
#pragma unroll
        for (int ni = 0; ni < 2; ni++) accA[mi][ni] = (floatx4)0.f;
    }
    for (int ks = 0; ks < 4; ks++) {
#pragma unroll
        for (int j = 0; j < 4; j++) {
            int u = tid + 256 * j;
            int row = u >> 4, cu = (u & 15) ^ (row & 15);
            gload16(sT + (size_t)(g * KC + row) * NPER + ks * 128 + cu * 8, &lS[u * 8]);
        }
#pragma unroll
        for (int j = 0; j < 8; j++) {
            int u = tid + 256 * j;
            int row = u >> 4, cu = (u & 15) ^ (row & 15);
            gload16(featT + (size_t)row * NN + g * NPER + ks * 128 + cu * 8, &lF[u * 8]);
        }
#pragma unroll
        for (int j = 0; j < 4; j++) {
            int u = tid + 256 * j;
            int row = u >> 4, cu = (u & 15) ^ (row & 15);
            gload16(asT + (size_t)(g * KC + row) * NPER + ks * 128 + cu * 8, &lAS[u * 8]);
        }
        __syncthreads();
#pragma unroll
        for (int kk = 0; kk < 4; kk++) {
            short8 aF[4];
#pragma unroll
            for (int mi = 0; mi < 4; mi++)
                aF[mi] = *reinterpret_cast<const short8*>(
                    &lS[((16 * mi + lm) * 16 + ((4 * kk + q) ^ lm)) * 8]);
            if (isH) {
                short8 bF[4];
#pragma unroll
                for (int ni = 0; ni < 4; ni++)
                    bF[ni] = *reinterpret_cast<const short8*>(
                        &lF[((64 * wv + 16 * ni + lm) * 16 + ((4 * kk + q) ^ lm)) * 8]);
#pragma unroll
                for (int mi = 0; mi < 4; mi++)
#pragma unroll
                    for (int ni = 0; ni < 4; ni++)
                        accH[mi][ni] = __builtin_amdgcn_mfma_f32_16x16x32_bf16(aF[mi], bF[ni],
                                                                               accH[mi][ni], 0, 0, 0);
            } else {
                short8 bF[2];
#pragma unroll
                for (int ni = 0; ni < 2; ni++)
                    bF[ni] = *reinterpret_cast<const short8*>(
                        &lAS[((32 * (wv - 2) + 16 * ni + lm) * 16 + ((4 * kk + q) ^ lm)) * 8]);
#pragma unroll
                for (int mi = 0; mi < 4; mi++)
#pragma unroll
                    for (int ni = 0; ni < 2; ni++)
                        accA[mi][ni] = __builtin_amdgcn_mfma_f32_16x16x32_bf16(aF[mi], bF[ni],
                                                                               accA[mi][ni], 0, 0, 0);
            }
        }
        __syncthreads();
    }
    if (isH) {
#pragma unroll
        for (int mi = 0; mi < 4; mi++)
#pragma unroll
            for (int ni = 0; ni < 4; ni++)
#pragma unroll
                for (int r = 0; r < 4; r++)
                    hnewf[(size_t)(g * KC + 16 * mi + 4 * q + r) * DD +
                          64 * wv + 16 * ni + lm] = accH[mi][ni][r];
    } else {
#pragma unroll
        for (int mi = 0; mi < 4; mi++)
#pragma unroll
            for (int ni = 0; ni < 2; ni++)
#pragma unroll
                for (int r = 0; r < 4; r++)
                    adjf[(size_t)(g * KC + 16 * mi + 4 * q + r) * AS +
                         g * KC + 32 * (wv - 2) + 16 * ni + lm] = accA[mi][ni][r];
    }
}

extern "C" void kernel_launch(void* const* d_in, const int* in_sizes, int n_in,
                              void* d_out, int out_size, void* d_ws, size_t ws_size,
                              hipStream_t stream) {
    const float* h   = (const float*)d_in[0];
    const float* Wf  = (const float*)d_in[1];
    const float* bfe = (const float*)d_in[2];
    const float* Wp  = (const float*)d_in[3];
    const float* bp  = (const float*)d_in[4];
    const int* esrc  = (const int*)d_in[5];
    const int* edst  = (const int*)d_in[6];

    float* adjf  = (float*)d_out;
    float* hnewf = adjf + (size_t)AS * AS;

    unsigned short* bundle = (unsigned short*)d_ws;        // NN*256 bf16
    unsigned short* WfT   = bundle + (size_t)NN * 256;     // 128*256
    unsigned short* WpT   = WfT + 128 * 256;               // 2048*256
    unsigned short* sT    = WpT + (size_t)AS * 256;        // NN*KC
    unsigned short* asT   = sT + (size_t)NN * KC;          // NN*KC
    unsigned short* featT = asT + (size_t)NN * KC;         // DD*NN
    unsigned short* hT    = featT + (size_t)DD * NN;       // DD*NN
    unsigned short* Aadj  = hT + (size_t)DD * NN;          // NN*512 bf16 (16 MB)
    unsigned int* Acnt = (unsigned int*)(Aadj + (size_t)NN * 512);  // NN*512 bytes
    float* Gf = (float*)(Acnt + (size_t)NN * 128);         // 256*256 fp32
    float* uF = Gf + 65536;                                // 256 fp32
    float* cF = uF + 256;                                  // 1 fp32 (+pad)
    unsigned short* Gb = (unsigned short*)(cF + 4);        // 256*256 bf16

    // zero Acnt + Gf + uF + cF in one shot (contiguous)
    hipMemsetAsync(Acnt, 0, (size_t)NN * 512 + (65536 + 256 + 4) * sizeof(float), stream);

    prep_kernel<<<1712, 256, 0, stream>>>(h, bundle, hT, esrc, edst, Acnt,
                                          Wf, Wp, bp, WfT, WpT, Gf, uF, cF);
    agg_h_mfma_kernel<<<260, 256, 0, stream>>>(Acnt, hT, bundle, Aadj, Gf, Gb);
    featpool_kernel<<<384, 256, 0, stream>>>(bundle, WfT, WpT, Gb, bfe, bp, uF, cF, featT, sT);
    as_mfma_kernel<<<NB * 2, 256, 0, stream>>>(sT, Aadj, asT);
    hnew_adj2_kernel<<<256, 256, 0, stream>>>(sT, featT, asT, adjf, hnewf);
}

// Round 13
// 162.906 us; speedup vs baseline: 1.1553x; 1.1553x over previous
//
#include <hip/hip_runtime.h>

#define NB   32
#define NPER 512
#define NN   16384
#define EE   262144
#define DD   128
#define AS   2048
#define KC   64

using short8   = __attribute__((ext_vector_type(8))) short;
using floatx4  = __attribute__((ext_vector_type(4))) float;
using ushort4v = __attribute__((ext_vector_type(4))) unsigned short;

typedef __attribute__((address_space(3))) unsigned int lds_u32;
typedef const __attribute__((address_space(1))) unsigned int gbl_u32;

static __device__ __forceinline__ void gload16(const unsigned short* g, unsigned short* l) {
    __builtin_amdgcn_global_load_lds((gbl_u32*)g, (lds_u32*)l, 16, 0, 0);
}
static __device__ __forceinline__ float bits2f(unsigned int u) {
    union { unsigned int i; float f; } z; z.i = u << 16; return z.f;
}
static __device__ __forceinline__ unsigned short f2b(float x) {
    union { float f; unsigned int u; } v; v.f = x;
    unsigned int r = v.u + 0x7fffu + ((v.u >> 16) & 1u);
    return (unsigned short)(r >> 16);
}
// exact for non-negative ints <= 256
static __device__ __forceinline__ unsigned short f2b_exact(float x) {
    union { float f; unsigned int u; } v; v.f = x;
    return (unsigned short)(v.u >> 16);
}

// ---- prep task grid (heavy first): 0-31 ggemm | 32-159 h-cast | 160-1183 edges
// ----                               | 1184-1727 W transposes ----
union PrepSMem {
    unsigned short fT[128 * 136];
    float tl[32][33];
    struct { unsigned short glA[4096]; unsigned short glB[4096]; float gcred[4]; } gg;
};
__global__ void prep_kernel(const float* __restrict__ h, unsigned short* __restrict__ bundle,
                            unsigned short* __restrict__ hT, const int* __restrict__ esrc,
                            const int* __restrict__ edst, unsigned int* __restrict__ Acnt,
                            const float* __restrict__ Wf, const float* __restrict__ Wp,
                            const float* __restrict__ bp,
                            unsigned short* __restrict__ WfT, unsigned short* __restrict__ WpT,
                            float* __restrict__ Gf, float* __restrict__ uF,
                            float* __restrict__ cF) {
    __shared__ PrepSMem sm;
    int b = blockIdx.x, t = threadIdx.x;
    if (b < 32) {
        // ggemm: G = Wp Wp^T from fp32 (K split 8 ways), in-register bf16 cast staging
        int ks = b >> 2, ti = (b >> 1) & 1, tj = b & 1;
        int wv = t >> 6, lane = t & 63;
        int mw = wv >> 1, nw = wv & 1, q = lane >> 4, lm = lane & 15;
        int swz = q ^ ((lm >> 1) & 3);
        floatx4 acc[4][4];
#pragma unroll
        for (int mi = 0; mi < 4; mi++)
#pragma unroll
            for (int ni = 0; ni < 4; ni++) acc[mi][ni] = (floatx4)0.f;
        for (int ki = 0; ki < 8; ki++) {
            int k0 = ks * 256 + ki * 32;
#pragma unroll
            for (int half = 0; half < 2; half++) {
                int u = t + 256 * half;
                int row = u >> 2, c = u & 3;
                int cs = c ^ ((row >> 1) & 3);
                const float4* sa = reinterpret_cast<const float4*>(
                    Wp + (size_t)(ti * 128 + row) * 2048 + k0 + c * 8);
                float4 v0 = sa[0], v1 = sa[1];
                ushort4v p0 = { f2b(v0.x), f2b(v0.y), f2b(v0.z), f2b(v0.w) };
                ushort4v p1 = { f2b(v1.x), f2b(v1.y), f2b(v1.z), f2b(v1.w) };
                *reinterpret_cast<ushort4v*>(&sm.gg.glA[(row * 4 + cs) * 8]) = p0;
                *reinterpret_cast<ushort4v*>(&sm.gg.glA[(row * 4 + cs) * 8 + 4]) = p1;
                const float4* sb = reinterpret_cast<const float4*>(
                    Wp + (size_t)(tj * 128 + row) * 2048 + k0 + c * 8);
                float4 w0 = sb[0], w1 = sb[1];
                ushort4v q0 = { f2b(w0.x), f2b(w0.y), f2b(w0.z), f2b(w0.w) };
                ushort4v q1 = { f2b(w1.x), f2b(w1.y), f2b(w1.z), f2b(w1.w) };
                *reinterpret_cast<ushort4v*>(&sm.gg.glB[(row * 4 + cs) * 8]) = q0;
                *reinterpret_cast<ushort4v*>(&sm.gg.glB[(row * 4 + cs) * 8 + 4]) = q1;
            }
            __syncthreads();
            short8 aF[4], bF[4];
#pragma unroll
            for (int mi = 0; mi < 4; mi++)
                aF[mi] = *reinterpret_cast<const short8*>(&sm.gg.glA[((64 * mw + 16 * mi + lm) * 4 + swz) * 8]);
#pragma unroll
            for (int ni = 0; ni < 4; ni++)
                bF[ni] = *reinterpret_cast<const short8*>(&sm.gg.glB[((64 * nw + 16 * ni + lm) * 4 + swz) * 8]);
#pragma unroll
            for (int mi = 0; mi < 4; mi++)
#pragma unroll
                for (int ni = 0; ni < 4; ni++)
                    acc[mi][ni] = __builtin_amdgcn_mfma_f32_16x16x32_bf16(aF[mi], bF[ni], acc[mi][ni], 0, 0, 0);
            __syncthreads();
        }
#pragma unroll
        for (int mi = 0; mi < 4; mi++)
#pragma unroll
            for (int ni = 0; ni < 4; ni++)
#pragma unroll
                for (int r = 0; r < 4; r++)
                    atomicAdd(&Gf[(size_t)(ti * 128 + 64 * mw + 16 * mi + 4 * q + r) * 256 +
                                  tj * 128 + 64 * nw + 16 * ni + lm], acc[mi][ni][r]);
        if (tj == 0) {
            // uF partial: rows ti*128..+128 over K segment ks*256..+256, float4 + pair-shuffle
            int row = t >> 1, jh = t & 1;
            const float4* wr = reinterpret_cast<const float4*>(
                Wp + (size_t)(ti * 128 + row) * 2048 + ks * 256 + jh * 128);
            const float4* br = reinterpret_cast<const float4*>(bp + ks * 256 + jh * 128);
            float s = 0.f;
#pragma unroll 8
            for (int j = 0; j < 32; j++) {
                float4 a = wr[j], c = br[j];
                s += a.x * c.x + a.y * c.y + a.z * c.z + a.w * c.w;
            }
            s += __shfl_xor(s, 1, 64);
            if (jh == 0) atomicAdd(&uF[ti * 128 + row], s);
        }
        if (b == 0) {
            float s = 0.f;
            for (int j = t; j < 2048; j += 256) { float v = bp[j]; s += v * v; }
#pragma unroll
            for (int d = 1; d < 64; d <<= 1) s += __shfl_xor(s, d, 64);
            if (lane == 0) sm.gg.gcred[wv] = s;
            __syncthreads();
            if (t == 0) atomicAdd(cF, sm.gg.gcred[0] + sm.gg.gcred[1] + sm.gg.gcred[2] + sm.gg.gcred[3]);
        }
    } else if (b < 160) {
        int node0 = (b - 32) * 128;
        int r = t >> 1, hf = t & 1;
        const float4* h4 = reinterpret_cast<const float4*>(h + (size_t)(node0 + r) * 128 + hf * 64);
        unsigned short* bo = bundle + (size_t)(node0 + r) * 256 + hf * 64;
#pragma unroll
        for (int i = 0; i < 16; i++) {
            float4 v = h4[i];
            ushort4v o = { f2b(v.x), f2b(v.y), f2b(v.z), f2b(v.w) };
            *reinterpret_cast<ushort4v*>(bo + 4 * i) = o;
            int c = hf * 64 + 4 * i;
            sm.fT[(c + 0) * 136 + r] = o.x;
            sm.fT[(c + 1) * 136 + r] = o.y;
            sm.fT[(c + 2) * 136 + r] = o.z;
            sm.fT[(c + 3) * 136 + r] = o.w;
        }
        __syncthreads();
        int c = t >> 1, nh = t & 1;
        const uint4* src = reinterpret_cast<const uint4*>(&sm.fT[c * 136 + nh * 64]);
        uint4* dst = reinterpret_cast<uint4*>(hT + (size_t)c * NN + node0 + nh * 64);
#pragma unroll
        for (int i = 0; i < 8; i++) dst[i] = src[i];
    } else if (b < 1184) {
        int e = (b - 160) * 256 + t;
        int d = edst[e], sl = esrc[e] & 511;
        int idx = d * 512 + sl;
        atomicAdd(&Acnt[idx >> 2], 1u << (8 * (idx & 3)));
    } else {
        int tb = b - 1184;
        int bx = tb % 68, by = tb / 68;
        int tx = t & 31, ty = t >> 5;
        const float* in; unsigned short* out; int C, cb;
        if (bx < DD / 32) { in = Wf; out = WfT; C = DD; cb = bx; }
        else              { in = Wp; out = WpT; C = AS; cb = bx - DD / 32; }
        int c0 = cb * 32, r0 = by * 32;
        for (int i = 0; i < 4; i++)
            sm.tl[ty + 8 * i][tx] = in[(size_t)(r0 + ty + 8 * i) * C + c0 + tx];
        __syncthreads();
        for (int i = 0; i < 4; i++)
            out[(size_t)(c0 + ty + 8 * i) * 256 + r0 + tx] = f2b(sm.tl[tx][ty + 8 * i]);
    }
}

__global__ __launch_bounds__(256) void agg_h_mfma_kernel(
    const unsigned int* __restrict__ Acnt, const unsigned short* __restrict__ hT,
    unsigned short* __restrict__ bundle, unsigned short* __restrict__ Aadj,
    const float* __restrict__ Gf, unsigned short* __restrict__ Gb) {
    __shared__ alignas(16) unsigned short lA[64 * 512];
    __shared__ float rs[64];
    int tid = threadIdx.x, bx = blockIdx.x;
    if (bx >= 256) {
        int base = (bx - 256) * 16384;
        for (int i = 0; i < 16; i++) {
            int idx = base + i * 1024 + tid * 4;
            float4 v = *reinterpret_cast<const float4*>(Gf + idx);
            ushort4v o = { f2b(v.x), f2b(v.y), f2b(v.z), f2b(v.w) };
            *reinterpret_cast<ushort4v*>(&Gb[idx]) = o;
        }
        return;
    }
    int r0 = bx * 64, g = bx >> 3;
    int wv = tid >> 6, lane = tid & 63, q = lane >> 4, lm = lane & 15;
    int mw = wv >> 1, nw = wv & 1;
    if (tid < 64) rs[tid] = 0.f;
    __syncthreads();
#pragma unroll
    for (int j = 0; j < 8; j++) {
        int ub = tid + 256 * j;
        int row = ub >> 5, kb = ub & 31;
        uint4 w = reinterpret_cast<const uint4*>(Acnt)[(size_t)(r0 + row) * 32 + kb];
        unsigned int wa[4] = { w.x, w.y, w.z, w.w };
        unsigned short ob[16];
        float sum = 0.f;
#pragma unroll
        for (int i = 0; i < 4; i++) {
#pragma unroll
            for (int bb = 0; bb < 4; bb++) {
                float fv = (float)((wa[i] >> (8 * bb)) & 0xffu);
                sum += fv;
                ob[4 * i + bb] = f2b_exact(fv);
            }
        }
        atomicAdd(&rs[row], sum);
        uint4* gdst = reinterpret_cast<uint4*>(&Aadj[(size_t)(r0 + row) * 512 + kb * 16]);
        gdst[0] = *reinterpret_cast<const uint4*>(&ob[0]);
        gdst[1] = *reinterpret_cast<const uint4*>(&ob[8]);
#pragma unroll
        for (int jj = 0; jj < 2; jj++) {
            int pos = (kb * 2 + jj) ^ (row & 7);
            *reinterpret_cast<uint4*>(&lA[(row * 64 + pos) * 8]) =
                *reinterpret_cast<const uint4*>(&ob[8 * jj]);
        }
    }
    floatx4 acc[2][4];
#pragma unroll
    for (int mt = 0; mt < 2; mt++)
#pragma unroll
        for (int nt = 0; nt < 4; nt++) acc[mt][nt] = (floatx4)0.f;
    __syncthreads();
    const unsigned short* Bb = hT + (size_t)(64 * nw + lm) * NN + g * 512 + (q << 3);
    short8 bF[2][4];
#pragma unroll
    for (int nt = 0; nt < 4; nt++)
        bF[0][nt] = *reinterpret_cast<const short8*>(Bb + (size_t)16 * nt * NN);
    for (int ki = 0; ki < 16; ki++) {
        if (ki < 15) {
#pragma unroll
            for (int nt = 0; nt < 4; nt++)
                bF[(ki + 1) & 1][nt] =
                    *reinterpret_cast<const short8*>(Bb + (size_t)16 * nt * NN + (ki + 1) * 32);
        }
        short8 aF[2];
        int swz = (4 * ki + q) ^ (lm & 7);
#pragma unroll
        for (int mt = 0; mt < 2; mt++)
            aF[mt] = *reinterpret_cast<const short8*>(&lA[((32 * mw + 16 * mt + lm) * 64 + swz) * 8]);
#pragma unroll
        for (int mt = 0; mt < 2; mt++)
#pragma unroll
            for (int nt = 0; nt < 4; nt++)
                acc[mt][nt] = __builtin_amdgcn_mfma_f32_16x16x32_bf16(aF[mt], bF[ki & 1][nt],
                                                                      acc[mt][nt], 0, 0, 0);
    }
#pragma unroll
    for (int mt = 0; mt < 2; mt++)
#pragma unroll
        for (int r = 0; r < 4; r++) {
            int row = 32 * mw + 16 * mt + 4 * q + r;
            float inv = 1.0f / fmaxf(rs[row], 1.0f);
#pragma unroll
            for (int nt = 0; nt < 4; nt++)
                bundle[(size_t)(r0 + row) * 256 + 128 + 64 * nw + 16 * nt + lm] =
                    f2b(acc[mt][nt][r] * inv);
        }
}

union FPSMem {
    struct { unsigned short lA[4096]; unsigned short lB[4096]; float red[256]; } feat;
    struct { unsigned short lA[16384]; float raw[4352]; float ssq[256]; float rn[64];
             float uL[256]; } pool;
};
__global__ __launch_bounds__(256) void featpool_kernel(
    const unsigned short* __restrict__ bundle, const unsigned short* __restrict__ WfT,
    const unsigned short* __restrict__ WpT, const unsigned short* __restrict__ Gb,
    const float* __restrict__ bfe, const float* __restrict__ bp,
    const float* __restrict__ uF, const float* __restrict__ cF,
    unsigned short* __restrict__ featT, unsigned short* __restrict__ sT) {
    __shared__ FPSMem sm;
    int tid = threadIdx.x, b = blockIdx.x;
    if (b < 128) {
        int r0 = b * 128;
        int wv = tid >> 6, lane = tid & 63;
        int mw = wv >> 1, nw = wv & 1, q = lane >> 4, lm = lane & 15;
        int rowS0 = tid >> 2,         cS0 = (tid & 3) ^ ((rowS0 >> 1) & 3);
        int rowS1 = (tid + 256) >> 2, cS1 = ((tid + 256) & 3) ^ ((rowS1 >> 1) & 3);
        int swz = q ^ ((lm >> 1) & 3);
        floatx4 acc[4][4];
#pragma unroll
        for (int mi = 0; mi < 4; mi++)
#pragma unroll
            for (int ni = 0; ni < 4; ni++) acc[mi][ni] = (floatx4)0.f;
        for (int k0 = 0; k0 < 256; k0 += 32) {
            gload16(bundle + (size_t)(r0 + rowS0) * 256 + k0 + 8 * cS0, &sm.feat.lA[tid * 8]);
            gload16(bundle + (size_t)(r0 + rowS1) * 256 + k0 + 8 * cS1, &sm.feat.lA[(tid + 256) * 8]);
            gload16(WfT + (size_t)rowS0 * 256 + k0 + 8 * cS0, &sm.feat.lB[tid * 8]);
            gload16(WfT + (size_t)rowS1 * 256 + k0 + 8 * cS1, &sm.feat.lB[(tid + 256) * 8]);
            __syncthreads();
            short8 aF[4], bF[4];
#pragma unroll
            for (int mi = 0; mi < 4; mi++)
                aF[mi] = *reinterpret_cast<const short8*>(&sm.feat.lA[((64 * mw + 16 * mi + lm) * 4 + swz) * 8]);
#pragma unroll
            for (int ni = 0; ni < 4; ni++)
                bF[ni] = *reinterpret_cast<const short8*>(&sm.feat.lB[((64 * nw + 16 * ni + lm) * 4 + swz) * 8]);
#pragma unroll
            for (int mi = 0; mi < 4; mi++)
#pragma unroll
                for (int ni = 0; ni < 4; ni++)
                    acc[mi][ni] = __builtin_amdgcn_mfma_f32_16x16x32_bf16(aF[mi], bF[ni], acc[mi][ni], 0, 0, 0);
            __syncthreads();
        }
#pragma unroll
        for (int ni = 0; ni < 4; ni++) {
            float bv = bfe[64 * nw + 16 * ni + lm];
#pragma unroll
            for (int mi = 0; mi < 4; mi++)
#pragma unroll
                for (int r = 0; r < 4; r++) acc[mi][ni][r] += bv;
        }
#pragma unroll
        for (int mi = 0; mi < 4; mi++)
#pragma unroll
            for (int r = 0; r < 4; r++) {
                float p = 0.f;
#pragma unroll
                for (int ni = 0; ni < 4; ni++) p += acc[mi][ni][r] * acc[mi][ni][r];
                p += __shfl_xor(p, 1, 64);
                p += __shfl_xor(p, 2, 64);
                p += __shfl_xor(p, 4, 64);
                p += __shfl_xor(p, 8, 64);
                if (lm == 0) sm.feat.red[nw * 128 + 64 * mw + 16 * mi + 4 * q + r] = p;
            }
        __syncthreads();
#pragma unroll
        for (int mi = 0; mi < 4; mi++) {
            float rrn[4];
#pragma unroll
            for (int r = 0; r < 4; r++) {
                int rl = 64 * mw + 16 * mi + 4 * q + r;
                rrn[r] = 1.0f / fmaxf(sqrtf(sm.feat.red[rl] + sm.feat.red[128 + rl]), 1e-12f);
            }
#pragma unroll
            for (int ni = 0; ni < 4; ni++) {
                int col = 64 * nw + 16 * ni + lm;
                ushort4v pk = { f2b(fmaxf(acc[mi][ni][0] * rrn[0], 0.f)),
                                f2b(fmaxf(acc[mi][ni][1] * rrn[1], 0.f)),
                                f2b(fmaxf(acc[mi][ni][2] * rrn[2], 0.f)),
                                f2b(fmaxf(acc[mi][ni][3] * rrn[3], 0.f)) };
                *reinterpret_cast<ushort4v*>(
                    &featT[(size_t)col * NN + r0 + 64 * mw + 16 * mi + 4 * q]) = pk;
            }
        }
    } else {
        int bx = b - 128;
        int r0 = bx * 64, g = bx >> 3;
        int wv = tid >> 6, lane = tid & 63, q = lane >> 4, lm = lane & 15;
#pragma unroll
        for (int j = 0; j < 8; j++) {
            int u = tid + 256 * j;
            int row = u >> 5;
            int chunk = (u & 31) ^ (row & 7);
            gload16(bundle + (size_t)(r0 + row) * 256 + chunk * 8, &sm.pool.lA[u * 8]);
        }
        sm.pool.uL[tid] = uF[tid];
        __syncthreads();
        {
            const unsigned short* Bb = Gb + ((size_t)(wv * 64 + lm) << 8) + (q << 3);
            short8 bF[2][4];
#pragma unroll
            for (int ni = 0; ni < 4; ni++)
                bF[0][ni] = *reinterpret_cast<const short8*>(Bb + (ni << 12));
            floatx4 acc[4][4];
#pragma unroll
            for (int mi = 0; mi < 4; mi++)
#pragma unroll
                for (int ni = 0; ni < 4; ni++) acc[mi][ni] = (floatx4)0.f;
#pragma unroll
            for (int k = 0; k < 8; k++) {
                if (k < 7) {
#pragma unroll
                    for (int ni = 0; ni < 4; ni++)
                        bF[(k + 1) & 1][ni] =
                            *reinterpret_cast<const short8*>(Bb + (ni << 12) + ((k + 1) << 5));
                }
                short8 aF[4];
                int swz = (4 * k + q) ^ (lm & 7);
#pragma unroll
                for (int mi = 0; mi < 4; mi++)
                    aF[mi] = *reinterpret_cast<const short8*>(&sm.pool.lA[((16 * mi + lm) * 32 + swz) * 8]);
#pragma unroll
                for (int mi = 0; mi < 4; mi++)
#pragma unroll
                    for (int ni = 0; ni < 4; ni++)
                        acc[mi][ni] = __builtin_amdgcn_mfma_f32_16x16x32_bf16(aF[mi], bF[k & 1][ni],
                                                                              acc[mi][ni], 0, 0, 0);
            }
            float uc[4];
#pragma unroll
            for (int ni = 0; ni < 4; ni++) uc[ni] = sm.pool.uL[64 * wv + 16 * ni + lm];
#pragma unroll
            for (int mi = 0; mi < 4; mi++)
#pragma unroll
                for (int r = 0; r < 4; r++) {
                    int row = 16 * mi + 4 * q + r;
                    float p = 0.f;
#pragma unroll
                    for (int ni = 0; ni < 4; ni++) {
                        int col = 64 * wv + 16 * ni + lm;
                        int cu = (col >> 3) ^ (row & 7);
                        float xv = bits2f((unsigned int)sm.pool.lA[(row * 32 + cu) * 8 + (col & 7)]);
                        p += (acc[mi][ni][r] + 2.f * uc[ni]) * xv;
                    }
                    p += __shfl_xor(p, 1, 64);
                    p += __shfl_xor(p, 2, 64);
                    p += __shfl_xor(p, 4, 64);
                    p += __shfl_xor(p, 8, 64);
                    if (lm == 0) sm.pool.ssq[wv * 64 + row] = p;
                }
        }
        {
            const unsigned short* Bb2 = WpT + (size_t)(g * KC + 16 * wv + lm) * 256 + (q << 3);
            short8 b2[2];
            b2[0] = *reinterpret_cast<const short8*>(Bb2);
            floatx4 acc2[4];
#pragma unroll
            for (int mi = 0; mi < 4; mi++) acc2[mi] = (floatx4)0.f;
#pragma unroll
            for (int k = 0; k < 8; k++) {
                if (k < 7) b2[(k + 1) & 1] = *reinterpret_cast<const short8*>(Bb2 + ((k + 1) << 5));
                short8 aF[4];
                int swz = (4 * k + q) ^ (lm & 7);
#pragma unroll
                for (int mi = 0; mi < 4; mi++)
                    aF[mi] = *reinterpret_cast<const short8*>(&sm.pool.lA[((16 * mi + lm) * 32 + swz) * 8]);
#pragma unroll
                for (int mi = 0; mi < 4; mi++)
                    acc2[mi] = __builtin_amdgcn_mfma_f32_16x16x32_bf16(aF[mi], b2[k & 1], acc2[mi], 0, 0, 0);
            }
            float bv = bp[g * KC + 16 * wv + lm];
#pragma unroll
            for (int mi = 0; mi < 4; mi++)
#pragma unroll
                for (int r = 0; r < 4; r++)
                    sm.pool.raw[(16 * mi + 4 * q + r) * 68 + 16 * wv + lm] = acc2[mi][r] + bv;
        }
        __syncthreads();
        if (tid < 64)
            sm.pool.rn[tid] = 1.0f / fmaxf(sqrtf(sm.pool.ssq[tid] + sm.pool.ssq[64 + tid] +
                                           sm.pool.ssq[128 + tid] + sm.pool.ssq[192 + tid] + cF[0]), 1e-12f);
        __syncthreads();
        {
            int row = tid >> 2, j = tid & 3;
            int nloc = ((bx & 7) << 6) + row;
            float rn = sm.pool.rn[row];
            float v[16];
            float mx = -1e30f;
#pragma unroll
            for (int c4 = 0; c4 < 4; c4++) {
                float4 rv = *reinterpret_cast<const float4*>(&sm.pool.raw[row * 68 + 16 * j + 4 * c4]);
                v[4 * c4 + 0] = fmaxf(rv.x * rn, 0.f);
                v[4 * c4 + 1] = fmaxf(rv.y * rn, 0.f);
                v[4 * c4 + 2] = fmaxf(rv.z * rn, 0.f);
                v[4 * c4 + 3] = fmaxf(rv.w * rn, 0.f);
            }
#pragma unroll
            for (int c = 0; c < 16; c++) mx = fmaxf(mx, v[c]);
            mx = fmaxf(mx, __shfl_xor(mx, 1, 64));
            mx = fmaxf(mx, __shfl_xor(mx, 2, 64));
            float z = 0.f;
#pragma unroll
            for (int c = 0; c < 16; c++) { v[c] = __expf(v[c] - mx); z += v[c]; }
            z += __shfl_xor(z, 1, 64);
            z += __shfl_xor(z, 2, 64);
            float iz = 1.0f / z;
#pragma unroll
            for (int c4 = 0; c4 < 4; c4++) {
                size_t tb = (size_t)(g * KC + 16 * j + 4 * c4) * NPER + nloc;
                sT[tb] = f2b(v[4 * c4 + 0] * iz);
                sT[tb + NPER] = f2b(v[4 * c4 + 1] * iz);
                sT[tb + 2 * NPER] = f2b(v[4 * c4 + 2] * iz);
                sT[tb + 3 * NPER] = f2b(v[4 * c4 + 3] * iz);
            }
        }
    }
}

__global__ __launch_bounds__(256) void as_mfma_kernel(
    const unsigned short* __restrict__ sT, const unsigned short* __restrict__ Aadj,
    unsigned short* __restrict__ asT) {
    __shared__ alignas(16) unsigned short lS[64 * 512];
    int tid = threadIdx.x, bx = blockIdx.x;
    int g = bx >> 1, half = bx & 1;
    int wv = tid >> 6, lane = tid & 63, q = lane >> 4, lm = lane & 15;
#pragma unroll
    for (int j = 0; j < 16; j++) {
        int u = tid + 256 * j;
        int row = u >> 6, cu = (u & 63) ^ (row & 7);
        gload16(sT + (size_t)(g * KC + row) * NPER + cu * 8, &lS[u * 8]);
    }
    floatx4 acc[4][4];
#pragma unroll
    for (int mi = 0; mi < 4; mi++)
#pragma unroll
        for (int nt = 0; nt < 4; nt++) acc[mi][nt] = (floatx4)0.f;
    __syncthreads();
    int dbase = half * 256 + wv * 64;
    const unsigned short* Bb = Aadj + (size_t)(g * 512 + dbase + lm) * 512 + (q << 3);
    short8 bF[2][4];
#pragma unroll
    for (int nt = 0; nt < 4; nt++)
        bF[0][nt] = *reinterpret_cast<const short8*>(Bb + (size_t)16 * nt * 512);
    for (int ki = 0; ki < 16; ki++) {
        if (ki < 15) {
#pragma unroll
            for (int nt = 0; nt < 4; nt++)
                bF[(ki + 1) & 1][nt] =
                    *reinterpret_cast<const short8*>(Bb + (size_t)16 * nt * 512 + (ki + 1) * 32);
        }
        short8 aF[4];
        int swz = (4 * ki + q) ^ (lm & 7);
#pragma unroll
        for (int mi = 0; mi < 4; mi++)
            aF[mi] = *reinterpret_cast<const short8*>(&lS[((16 * mi + lm) * 64 + swz) * 8]);
#pragma unroll
        for (int mi = 0; mi < 4; mi++)
#pragma unroll
            for (int nt = 0; nt < 4; nt++)
                acc[mi][nt] = __builtin_amdgcn_mfma_f32_16x16x32_bf16(aF[mi], bF[ki & 1][nt],
                                                                      acc[mi][nt], 0, 0, 0);
    }
#pragma unroll
    for (int mi = 0; mi < 4; mi++)
#pragma unroll
        for (int r = 0; r < 4; r++) {
            int row = 16 * mi + 4 * q + r;
#pragma unroll
            for (int nt = 0; nt < 4; nt++)
                asT[(size_t)(g * KC + row) * NPER + dbase + 16 * nt + lm] = f2b(acc[mi][nt][r]);
        }
}

__global__ __launch_bounds__(256) void hnew_adj2_kernel(
    const unsigned short* __restrict__ sT, const unsigned short* __restrict__ featT,
    const unsigned short* __restrict__ asT, float* __restrict__ adjf,
    float* __restrict__ hnewf) {
    __shared__ alignas(16) unsigned short lS[1024 * 8];
    __shared__ alignas(16) unsigned short lF[2048 * 8];
    __shared__ alignas(16) unsigned short lAS[1024 * 8];
    int tid = threadIdx.x, b = blockIdx.x;
    if (b >= 32) {
        uint4 z = { 0u, 0u, 0u, 0u };
        for (int row = b - 32; row < AS; row += 224) {
            int g = row >> 6;
            uint4* out = reinterpret_cast<uint4*>(adjf + (size_t)row * AS);
            for (int i = tid; i < 512; i += 256)
                if (i < g * 16 || i >= g * 16 + 16) out[i] = z;
        }
        return;
    }
    int g = b;
    int wv = tid >> 6, lane = tid & 63, q = lane >> 4, lm = lane & 15;
    bool isH = (wv < 2);
    floatx4 accH[4][4];
    floatx4 accA[4][2];
#pragma unroll
    for (int mi = 0; mi < 4; mi++) {
#pragma unroll
        for (int ni = 0; ni < 4; ni++) accH[mi][ni] = (floatx4)0.f;
#pragma unroll
        for (int ni = 0; ni < 2; ni++) accA[mi][ni] = (floatx4)0.f;
    }
    for (int ks = 0; ks < 4; ks++) {
#pragma unroll
        for (int j = 0; j < 4; j++) {
            int u = tid + 256 * j;
            int row = u >> 4, cu = (u & 15) ^ (row & 15);
            gload16(sT + (size_t)(g * KC + row) * NPER + ks * 128 + cu * 8, &lS[u * 8]);
        }
#pragma unroll
        for (int j = 0; j < 8; j++) {
            int u = tid + 256 * j;
            int row = u >> 4, cu = (u & 15) ^ (row & 15);
            gload16(featT + (size_t)row * NN + g * NPER + ks * 128 + cu * 8, &lF[u * 8]);
        }
#pragma unroll
        for (int j = 0; j < 4; j++) {
            int u = tid + 256 * j;
            int row = u >> 4, cu = (u & 15) ^ (row & 15);
            gload16(asT + (size_t)(g * KC + row) * NPER + ks * 128 + cu * 8, &lAS[u * 8]);
        }
        __syncthreads();
#pragma unroll
        for (int kk = 0; kk < 4; kk++) {
            short8 aF[4];
#pragma unroll
            for (int mi = 0; mi < 4; mi++)
                aF[mi] = *reinterpret_cast<const short8*>(
                    &lS[((16 * mi + lm) * 16 + ((4 * kk + q) ^ lm)) * 8]);
            if (isH) {
                short8 bF[4];
#pragma unroll
                for (int ni = 0; ni < 4; ni++)
                    bF[ni] = *reinterpret_cast<const short8*>(
                        &lF[((64 * wv + 16 * ni + lm) * 16 + ((4 * kk + q) ^ lm)) * 8]);
#pragma unroll
                for (int mi = 0; mi < 4; mi++)
#pragma unroll
                    for (int ni = 0; ni < 4; ni++)
                        accH[mi][ni] = __builtin_amdgcn_mfma_f32_16x16x32_bf16(aF[mi], bF[ni],
                                                                               accH[mi][ni], 0, 0, 0);
            } else {
                short8 bF[2];
#pragma unroll
                for (int ni = 0; ni < 2; ni++)
                    bF[ni] = *reinterpret_cast<const short8*>(
                        &lAS[((32 * (wv - 2) + 16 * ni + lm) * 16 + ((4 * kk + q) ^ lm)) * 8]);
#pragma unroll
                for (int mi = 0; mi < 4; mi++)
#pragma unroll
                    for (int ni = 0; ni < 2; ni++)
                        accA[mi][ni] = __builtin_amdgcn_mfma_f32_16x16x32_bf16(aF[mi], bF[ni],
                                                                               accA[mi][ni], 0, 0, 0);
            }
        }
        __syncthreads();
    }
    if (isH) {
#pragma unroll
        for (int mi = 0; mi < 4; mi++)
#pragma unroll
            for (int ni = 0; ni < 4; ni++)
#pragma unroll
                for (int r = 0; r < 4; r++)
                    hnewf[(size_t)(g * KC + 16 * mi + 4 * q + r) * DD +
                          64 * wv + 16 * ni + lm] = accH[mi][ni][r];
    } else {
#pragma unroll
        for (int mi = 0; mi < 4; mi++)
#pragma unroll
            for (int ni = 0; ni < 2; ni++)
#pragma unroll
                for (int r = 0; r < 4; r++)
                    adjf[(size_t)(g * KC + 16 * mi + 4 * q + r) * AS +
                         g * KC + 32 * (wv - 2) + 16 * ni + lm] = accA[mi][ni][r];
    }
}

extern "C" void kernel_launch(void* const* d_in, const int* in_sizes, int n_in,
                              void* d_out, int out_size, void* d_ws, size_t ws_size,
                              hipStream_t stream) {
    const float* h   = (const float*)d_in[0];
    const float* Wf  = (const float*)d_in[1];
    const float* bfe = (const float*)d_in[2];
    const float* Wp  = (const float*)d_in[3];
    const float* bp  = (const float*)d_in[4];
    const int* esrc  = (const int*)d_in[5];
    const int* edst  = (const int*)d_in[6];

    float* adjf  = (float*)d_out;
    float* hnewf = adjf + (size_t)AS * AS;

    unsigned short* bundle = (unsigned short*)d_ws;        // NN*256 bf16
    unsigned short* WfT   = bundle + (size_t)NN * 256;     // 128*256
    unsigned short* WpT   = WfT + 128 * 256;               // 2048*256
    unsigned short* sT    = WpT + (size_t)AS * 256;        // NN*KC
    unsigned short* asT   = sT + (size_t)NN * KC;          // NN*KC
    unsigned short* featT = asT + (size_t)NN * KC;         // DD*NN
    unsigned short* hT    = featT + (size_t)DD * NN;       // DD*NN
    unsigned short* Aadj  = hT + (size_t)DD * NN;          // NN*512 bf16 (16 MB)
    unsigned int* Acnt = (unsigned int*)(Aadj + (size_t)NN * 512);  // NN*512 bytes
    float* Gf = (float*)(Acnt + (size_t)NN * 128);         // 256*256 fp32
    float* uF = Gf + 65536;                                // 256 fp32
    float* cF = uF + 256;                                  // 1 fp32 (+pad)
    unsigned short* Gb = (unsigned short*)(cF + 4);        // 256*256 bf16

    // zero Acnt + Gf + uF + cF in one shot (contiguous)
    hipMemsetAsync(Acnt, 0, (size_t)NN * 512 + (65536 + 256 + 4) * sizeof(float), stream);

    prep_kernel<<<1728, 256, 0, stream>>>(h, bundle, hT, esrc, edst, Acnt,
                                          Wf, Wp, bp, WfT, WpT, Gf, uF, cF);
    agg_h_mfma_kernel<<<260, 256, 0, stream>>>(Acnt, hT, bundle, Aadj, Gf, Gb);
    featpool_kernel<<<384, 256, 0, stream>>>(bundle, WfT, WpT, Gb, bfe, bp, uF, cF, featT, sT);
    as_mfma_kernel<<<NB * 2, 256, 0, stream>>>(sT, Aadj, asT);
    hnew_adj2_kernel<<<256, 256, 0, stream>>>(sT, featT, asT, adjf, hnewf);
}